// Round 1
// baseline (176.775 us; speedup 1.0000x reference)
//
#include <hip/hip_runtime.h>
#include <hip/hip_bf16.h>

typedef __attribute__((ext_vector_type(8))) short short8;
typedef __attribute__((ext_vector_type(4))) float f32x4;
typedef __attribute__((ext_vector_type(4))) unsigned short ushort4v;

#define DEV static __device__ __forceinline__

DEV unsigned short f2bf(float f){
  unsigned u = __float_as_uint(f);
  u += 0x7fffu + ((u >> 16) & 1u);     // round-to-nearest-even
  return (unsigned short)(u >> 16);
}

// Problem constants: B=2, C=64, H=W=64 -> S=4096, NH=4, HD=16, GROUPS=32 (2 ch/group)

// ---------------- K1: GroupNorm statistics (mean, rstd per (b,group)) ----------------
__global__ __launch_bounds__(256) void gn_stats_k(const float* __restrict__ x,
                                                  float* __restrict__ stats){
  int g = blockIdx.x;                       // g = b*32 + grp ; contiguous 8192 floats
  const float* p = x + (size_t)g * 8192;
  float sum = 0.f, sq = 0.f;
  for (int i = threadIdx.x * 4; i < 8192; i += 1024){
    float4 v = *(const float4*)(p + i);
    sum += v.x + v.y + v.z + v.w;
    sq  += v.x*v.x + v.y*v.y + v.z*v.z + v.w*v.w;
  }
  #pragma unroll
  for (int off = 1; off < 64; off <<= 1){
    sum += __shfl_xor(sum, off);
    sq  += __shfl_xor(sq , off);
  }
  __shared__ float red[8];
  int w = threadIdx.x >> 6;
  if ((threadIdx.x & 63) == 0){ red[w*2] = sum; red[w*2+1] = sq; }
  __syncthreads();
  if (threadIdx.x == 0){
    float ts = red[0]+red[2]+red[4]+red[6];
    float tq = red[1]+red[3]+red[5]+red[7];
    float mean = ts * (1.f/8192.f);
    float var  = tq * (1.f/8192.f) - mean*mean;
    stats[g*2+0] = mean;
    stats[g*2+1] = rsqrtf(var + 1e-5f);
  }
}

// ---------------- K2: fused GroupNorm-apply + QKV 1x1 conv -> bf16 q,k,v ----------------
// q,k,v layout: [bn=b*4+n][s][d]  (d=16 contiguous). q pre-scaled by 1/sqrt(C)=0.125.
__global__ __launch_bounds__(256) void qkv_k(const float* __restrict__ x,
    const float* __restrict__ stats, const float* __restrict__ gsc,
    const float* __restrict__ gbi, const float* __restrict__ wq,
    unsigned short* __restrict__ q, unsigned short* __restrict__ k,
    unsigned short* __restrict__ v){
  int b  = blockIdx.x >> 7;
  int s0 = (blockIdx.x & 127) * 32;
  __shared__ float A[64][33];          // [c][s_local], +1 pad
  __shared__ float W[192*64];
  int t = threadIdx.x;
  for (int i = t; i < 3072; i += 256) ((float4*)W)[i] = ((const float4*)wq)[i];
  {
    int c  = t >> 2;
    int s8 = (t & 3) * 8;
    const float* px = x + ((size_t)b*64 + c)*4096 + s0 + s8;
    float4 v0 = *(const float4*)px;
    float4 v1 = *(const float4*)(px + 4);
    int gg = b*32 + (c >> 1);
    float mu = stats[gg*2], rs = stats[gg*2+1];
    float sc = gsc[c] * rs;
    float bi = gbi[c] - mu * sc;
    A[c][s8+0]=v0.x*sc+bi; A[c][s8+1]=v0.y*sc+bi; A[c][s8+2]=v0.z*sc+bi; A[c][s8+3]=v0.w*sc+bi;
    A[c][s8+4]=v1.x*sc+bi; A[c][s8+5]=v1.y*sc+bi; A[c][s8+6]=v1.z*sc+bi; A[c][s8+7]=v1.w*sc+bi;
  }
  __syncthreads();
  int sl = t & 31, grp = t >> 5;       // o = grp + j*8
  float acc[24];
  #pragma unroll
  for (int j = 0; j < 24; ++j) acc[j] = 0.f;
  for (int c = 0; c < 64; ++c){
    float a = A[c][sl];
    #pragma unroll
    for (int j = 0; j < 24; ++j)
      acc[j] = fmaf(W[(grp + j*8)*64 + c], a, acc[j]);
  }
  int s = s0 + sl;
  #pragma unroll
  for (int j = 0; j < 24; ++j){
    int o = grp + j*8;
    int n = o / 48, r = o % 48;        // reshape [B,4,48,H,W]; split 16/16/16 -> q,k,v
    size_t base = (((size_t)b*4 + n)*4096 + s)*16;
    float val = acc[j];
    if (r < 16)       q[base + r]      = f2bf(val * 0.125f);
    else if (r < 32)  k[base + r - 16] = f2bf(val);
    else              v[base + r - 32] = f2bf(val);
  }
}

// ---------------- K3: flash attention ----------------
// grid 512 = 8 bn * 64 q-tiles ; 4 waves/block ; wave w owns q rows [qt*64+w*16, +16)
__global__ __launch_bounds__(256) void attn_k(const unsigned short* __restrict__ qb,
    const unsigned short* __restrict__ kb, const unsigned short* __restrict__ vb,
    float* __restrict__ ob){
  int bn = blockIdx.x >> 6;
  int qt = blockIdx.x & 63;
  const unsigned short* Qp = qb + (((size_t)bn*4096) + qt*64)*16;
  const unsigned short* Kp = kb + ((size_t)bn*4096)*16;
  const unsigned short* Vp = vb + ((size_t)bn*4096)*16;
  float* Op = ob + (((size_t)bn*4096) + qt*64)*16;

  int t = threadIdx.x;
  int w  = t >> 6;
  int l  = t & 63;
  int lr = l & 15;        // A-row / B-col / D-col lane index
  int lg = l >> 4;        // lane group 0..3

  __shared__ alignas(16) unsigned short Vt[16][72];     // V^T tile: [d][kv], stride 144B
  __shared__ alignas(16) unsigned short P[4][16][72];   // per-wave P: [q][kv]

  // Q fragment (A layout): lane holds Q[q=lr][k=lg*8+i], k padded 16->32 with zeros
  short8 qf = {};
  if (lg < 2) qf = *(const short8*)(Qp + (size_t)(w*16 + lr)*16 + lg*8);

  f32x4 zero = {0.f, 0.f, 0.f, 0.f};
  f32x4 Oacc = zero;                   // O[q=lg*4+r][d=lr]
  float m[4], lsum[4];
  #pragma unroll
  for (int r = 0; r < 4; ++r){ m[r] = -__builtin_inff(); lsum[r] = 0.f; }

  for (int kt = 0; kt < 64; ++kt){
    int kv0 = kt * 64;
    __syncthreads();                               // Vt/P from prev iter consumed
    {   // stage V^T cooperatively: 64 kv x 16 d
      int kv = t >> 2;
      int d4 = (t & 3) * 4;
      ushort4v vv = *(const ushort4v*)(Vp + (size_t)(kv0 + kv)*16 + d4);
      Vt[d4+0][kv] = vv[0];
      Vt[d4+1][kv] = vv[1];
      Vt[d4+2][kv] = vv[2];
      Vt[d4+3][kv] = vv[3];
    }
    // S = Q K^T : 4 MFMAs cover kv chunk of 64 ; S[q=lg*4+r][kv=c16*16+lr]
    f32x4 sc[4];
    #pragma unroll
    for (int c16 = 0; c16 < 4; ++c16){
      short8 kf = {};
      if (lg < 2) kf = *(const short8*)(Kp + (size_t)(kv0 + c16*16 + lr)*16 + lg*8);
      sc[c16] = __builtin_amdgcn_mfma_f32_16x16x32_bf16(qf, kf, zero, 0, 0, 0);
    }
    // online softmax per q row (rows live on 16-lane groups; reduce over lr and c16)
    #pragma unroll
    for (int r = 0; r < 4; ++r){
      float mx = fmaxf(fmaxf(sc[0][r], sc[1][r]), fmaxf(sc[2][r], sc[3][r]));
      #pragma unroll
      for (int off = 1; off < 16; off <<= 1) mx = fmaxf(mx, __shfl_xor(mx, off));
      float mn = fmaxf(m[r], mx);
      float alpha = __expf(m[r] - mn);             // first iter: exp(-inf)=0
      float rowsum = 0.f;
      float pv[4];
      #pragma unroll
      for (int c16 = 0; c16 < 4; ++c16){
        pv[c16] = __expf(sc[c16][r] - mn);
        rowsum += pv[c16];
      }
      #pragma unroll
      for (int off = 1; off < 16; off <<= 1) rowsum += __shfl_xor(rowsum, off);
      lsum[r] = lsum[r]*alpha + rowsum;
      m[r] = mn;
      Oacc[r] *= alpha;
      #pragma unroll
      for (int c16 = 0; c16 < 4; ++c16)
        P[w][lg*4 + r][c16*16 + lr] = f2bf(pv[c16]);
    }
    __syncthreads();                               // Vt + P visible
    // O += P @ V : A=P[q][kv], B=V[kv][d] (read from Vt transposed -> b128)
    #pragma unroll
    for (int u = 0; u < 2; ++u){
      short8 pf = *(const short8*)(&P[w][lr][lg*8 + u*32]);
      short8 vf = *(const short8*)(&Vt[lr][lg*8 + u*32]);
      Oacc = __builtin_amdgcn_mfma_f32_16x16x32_bf16(pf, vf, Oacc, 0, 0, 0);
    }
  }
  #pragma unroll
  for (int r = 0; r < 4; ++r)
    Op[(size_t)(w*16 + lg*4 + r)*16 + lr] = Oacc[r] / lsum[r];
}

// ---------------- K4: out 1x1 conv + bias + residual ----------------
__global__ __launch_bounds__(256) void oproj_k(const float* __restrict__ ob,
    const float* __restrict__ wo, const float* __restrict__ bo,
    const float* __restrict__ x, float* __restrict__ out){
  int b  = blockIdx.x >> 7;
  int s0 = (blockIdx.x & 127) * 32;
  __shared__ float A[64][33];
  __shared__ float W[4096];
  int t = threadIdx.x;
  for (int i = t; i < 1024; i += 256) ((float4*)W)[i] = ((const float4*)wo)[i];
  {
    int sl = t & 31;
    int nd = t >> 5;
    int n = nd >> 1, d0 = (nd & 1) * 8;
    const float* p = ob + ((((size_t)b*4 + n)*4096) + s0 + sl)*16 + d0;
    float4 u0 = *(const float4*)p;
    float4 u1 = *(const float4*)(p + 4);
    int c = n*16 + d0;
    A[c+0][sl]=u0.x; A[c+1][sl]=u0.y; A[c+2][sl]=u0.z; A[c+3][sl]=u0.w;
    A[c+4][sl]=u1.x; A[c+5][sl]=u1.y; A[c+6][sl]=u1.z; A[c+7][sl]=u1.w;
  }
  __syncthreads();
  int sl = t & 31, grp = t >> 5;
  float acc[8];
  #pragma unroll
  for (int j = 0; j < 8; ++j) acc[j] = 0.f;
  for (int c = 0; c < 64; ++c){
    float a = A[c][sl];
    #pragma unroll
    for (int j = 0; j < 8; ++j) acc[j] = fmaf(W[(grp + j*8)*64 + c], a, acc[j]);
  }
  int s = s0 + sl;
  #pragma unroll
  for (int j = 0; j < 8; ++j){
    int o = grp + j*8;
    size_t idx = ((size_t)b*64 + o)*4096 + s;
    out[idx] = acc[j] + bo[o] + x[idx];
  }
}

extern "C" void kernel_launch(void* const* d_in, const int* in_sizes, int n_in,
                              void* d_out, int out_size, void* d_ws, size_t ws_size,
                              hipStream_t stream){
  const float* x   = (const float*)d_in[0];
  const float* gsc = (const float*)d_in[1];
  const float* gbi = (const float*)d_in[2];
  const float* wq  = (const float*)d_in[3];
  const float* wo  = (const float*)d_in[4];
  const float* bo  = (const float*)d_in[5];
  float* out = (float*)d_out;

  char* ws = (char*)d_ws;
  float* stats        = (float*)ws;                              // 128 floats
  unsigned short* q   = (unsigned short*)(ws + 1024);            // 1 MB
  unsigned short* k   = (unsigned short*)(ws + 1024 + 1048576);  // 1 MB
  unsigned short* v   = (unsigned short*)(ws + 1024 + 2097152);  // 1 MB
  float* ob           = (float*)(ws + 1024 + 3145728);           // 2 MB

  gn_stats_k<<<64,  256, 0, stream>>>(x, stats);
  qkv_k     <<<256, 256, 0, stream>>>(x, stats, gsc, gbi, wq, q, k, v);
  attn_k    <<<512, 256, 0, stream>>>(q, k, v, ob);
  oproj_k   <<<256, 256, 0, stream>>>(ob, wo, bo, x, out);
}

// Round 2
// 77.334 us; speedup vs baseline: 2.2859x; 2.2859x over previous
//
#include <hip/hip_runtime.h>
#include <hip/hip_bf16.h>

typedef __attribute__((ext_vector_type(8))) short short8;
typedef __attribute__((ext_vector_type(4))) float f32x4;
typedef __attribute__((ext_vector_type(4))) unsigned short ushort4v;

#define DEV static __device__ __forceinline__

DEV unsigned short f2bf(float f){
  unsigned u = __float_as_uint(f);
  u += 0x7fffu + ((u >> 16) & 1u);     // round-to-nearest-even
  return (unsigned short)(u >> 16);
}

DEV unsigned pack2bf(float a, float b){
  __hip_bfloat162 h = __float22bfloat162_rn(make_float2(a, b));
  unsigned u;
  __builtin_memcpy(&u, &h, 4);
  return u;
}

// Problem constants: B=2, C=64, H=W=64 -> S=4096, NH=4, HD=16, GROUPS=32
#define NSPLIT 4
#define KVCHUNK 1024            // 4096 / NSPLIT
#define QSCALE 0.180336880111f  // 0.125 * log2(e): softmax in exp2 domain

// ---------------- K1: GroupNorm statistics ----------------
__global__ __launch_bounds__(256) void gn_stats_k(const float* __restrict__ x,
                                                  float* __restrict__ stats){
  int g = blockIdx.x;
  const float* p = x + (size_t)g * 8192;
  float sum = 0.f, sq = 0.f;
  for (int i = threadIdx.x * 4; i < 8192; i += 1024){
    float4 v = *(const float4*)(p + i);
    sum += v.x + v.y + v.z + v.w;
    sq  += v.x*v.x + v.y*v.y + v.z*v.z + v.w*v.w;
  }
  #pragma unroll
  for (int off = 1; off < 64; off <<= 1){
    sum += __shfl_xor(sum, off);
    sq  += __shfl_xor(sq , off);
  }
  __shared__ float red[8];
  int w = threadIdx.x >> 6;
  if ((threadIdx.x & 63) == 0){ red[w*2] = sum; red[w*2+1] = sq; }
  __syncthreads();
  if (threadIdx.x == 0){
    float ts = red[0]+red[2]+red[4]+red[6];
    float tq = red[1]+red[3]+red[5]+red[7];
    float mean = ts * (1.f/8192.f);
    float var  = tq * (1.f/8192.f) - mean*mean;
    stats[g*2+0] = mean;
    stats[g*2+1] = rsqrtf(var + 1e-5f);
  }
}

// ---------------- K2: fused GroupNorm-apply + QKV 1x1 conv -> bf16 ----------------
// q,k,v layout: [bn][s][d]. q pre-scaled by 0.125*log2e.
__global__ __launch_bounds__(256) void qkv_k(const float* __restrict__ x,
    const float* __restrict__ stats, const float* __restrict__ gsc,
    const float* __restrict__ gbi, const float* __restrict__ wq,
    unsigned short* __restrict__ q, unsigned short* __restrict__ k,
    unsigned short* __restrict__ v){
  int b  = blockIdx.x >> 7;
  int s0 = (blockIdx.x & 127) * 32;
  __shared__ float A[64][33];
  __shared__ float W[192*64];
  int t = threadIdx.x;
  for (int i = t; i < 3072; i += 256) ((float4*)W)[i] = ((const float4*)wq)[i];
  {
    int c  = t >> 2;
    int s8 = (t & 3) * 8;
    const float* px = x + ((size_t)b*64 + c)*4096 + s0 + s8;
    float4 v0 = *(const float4*)px;
    float4 v1 = *(const float4*)(px + 4);
    int gg = b*32 + (c >> 1);
    float mu = stats[gg*2], rs = stats[gg*2+1];
    float sc = gsc[c] * rs;
    float bi = gbi[c] - mu * sc;
    A[c][s8+0]=v0.x*sc+bi; A[c][s8+1]=v0.y*sc+bi; A[c][s8+2]=v0.z*sc+bi; A[c][s8+3]=v0.w*sc+bi;
    A[c][s8+4]=v1.x*sc+bi; A[c][s8+5]=v1.y*sc+bi; A[c][s8+6]=v1.z*sc+bi; A[c][s8+7]=v1.w*sc+bi;
  }
  __syncthreads();
  int sl = t & 31, grp = t >> 5;
  float acc[24];
  #pragma unroll
  for (int j = 0; j < 24; ++j) acc[j] = 0.f;
  for (int c = 0; c < 64; ++c){
    float a = A[c][sl];
    #pragma unroll
    for (int j = 0; j < 24; ++j)
      acc[j] = fmaf(W[(grp + j*8)*64 + c], a, acc[j]);
  }
  int s = s0 + sl;
  #pragma unroll
  for (int j = 0; j < 24; ++j){
    int o = grp + j*8;
    int n = o / 48, r = o % 48;
    size_t base = (((size_t)b*4 + n)*4096 + s)*16;
    float val = acc[j];
    if (r < 16)       q[base + r]      = f2bf(val * QSCALE);
    else if (r < 32)  k[base + r - 16] = f2bf(val);
    else              v[base + r - 32] = f2bf(val);
  }
}

// ---------------- K3: flash attention, KV-split, swapped-QK^T softmax ----------------
// grid 2048 = 8 bn * NSPLIT * 64 qt ; 4 waves/block ; wave w: q rows qt*64+w*16..+15
// Outputs UNNORMALIZED O partials + (m, l) per (split, bn, q) in log2 domain.
__global__ __launch_bounds__(256, 6) void attn_k(const unsigned short* __restrict__ qb,
    const unsigned short* __restrict__ kb, const unsigned short* __restrict__ vb,
    float* __restrict__ part, float* __restrict__ ml){
  int blk = blockIdx.x;
  int qt = blk & 63;
  int sp = (blk >> 6) & (NSPLIT-1);
  int bn = blk >> 8;

  const unsigned short* Kp = kb + (((size_t)bn*4096) + sp*KVCHUNK)*16;
  const unsigned short* Vp = vb + (((size_t)bn*4096) + sp*KVCHUNK)*16;

  int t = threadIdx.x;
  int w = t >> 6, l = t & 63, lr = l & 15, lg = l >> 4;

  const unsigned short* Qp = qb + (((size_t)bn*4096) + qt*64 + w*16)*16;

  __shared__ alignas(16) unsigned short Vt[16][72];     // V^T tile (cooperative)
  __shared__ alignas(16) unsigned short P[4][16][72];   // per-wave P: [q][kv]

  // Q as B-frag: lane holds Q[q=lr][d=lg*8+i], d padded 16->32 with zeros
  short8 qf = {};
  if (lg < 2) qf = *(const short8*)(Qp + (size_t)lr*16 + lg*8);

  f32x4 zero = {0.f,0.f,0.f,0.f};
  f32x4 Oacc = zero;                 // O[q=lg*4+r][d=lr]
  float m = -__builtin_inff(), lsum = 0.f;

  int skv = t >> 2, sd4 = (t & 3) * 4;   // cooperative V staging indices

  // prologue prefetch (tile 0)
  short8 kf[4];
  #pragma unroll
  for (int c = 0; c < 4; ++c){
    kf[c] = short8{};
    if (lg < 2) kf[c] = *(const short8*)(Kp + (size_t)(c*16 + lr)*16 + lg*8);
  }
  ushort4v vv = *(const ushort4v*)(Vp + (size_t)skv*16 + sd4);

  for (int kt = 0; kt < KVCHUNK/64; ++kt){
    __syncthreads();                             // prev PV done with Vt
    Vt[sd4+0][skv] = vv[0]; Vt[sd4+1][skv] = vv[1];
    Vt[sd4+2][skv] = vv[2]; Vt[sd4+3][skv] = vv[3];

    // prefetch next tile (overlaps softmax + PV below)
    short8 kn[4] = {short8{},short8{},short8{},short8{}};
    ushort4v vn = {};
    if (kt < KVCHUNK/64 - 1){
      int kv0n = (kt+1)*64;
      #pragma unroll
      for (int c = 0; c < 4; ++c)
        if (lg < 2) kn[c] = *(const short8*)(Kp + (size_t)(kv0n + c*16 + lr)*16 + lg*8);
      vn = *(const ushort4v*)(Vp + (size_t)(kv0n + skv)*16 + sd4);
    }

    // S^T = K Q^T : lane holds S[kv=c*16+4lg+r][q=lr]
    f32x4 sc[4];
    #pragma unroll
    for (int c = 0; c < 4; ++c)
      sc[c] = __builtin_amdgcn_mfma_f32_16x16x32_bf16(kf[c], qf, zero, 0, 0, 0);

    // online softmax for q=lr: in-lane tree + 2 shuffles (lanes lg..lg^3 share q)
    float x0 = fmaxf(fmaxf(sc[0][0],sc[0][1]), fmaxf(sc[0][2],sc[0][3]));
    float x1 = fmaxf(fmaxf(sc[1][0],sc[1][1]), fmaxf(sc[1][2],sc[1][3]));
    float x2 = fmaxf(fmaxf(sc[2][0],sc[2][1]), fmaxf(sc[2][2],sc[2][3]));
    float x3 = fmaxf(fmaxf(sc[3][0],sc[3][1]), fmaxf(sc[3][2],sc[3][3]));
    float mx = fmaxf(fmaxf(x0,x1), fmaxf(x2,x3));
    mx = fmaxf(mx, __shfl_xor(mx, 16));
    mx = fmaxf(mx, __shfl_xor(mx, 32));
    float mn = fmaxf(m, mx);
    float alpha = __builtin_amdgcn_exp2f(m - mn);   // iter 0: exp2(-inf)=0

    float rs0 = 0.f, rs1 = 0.f;
    #pragma unroll
    for (int c = 0; c < 4; ++c){
      float e0 = __builtin_amdgcn_exp2f(sc[c][0] - mn);
      float e1 = __builtin_amdgcn_exp2f(sc[c][1] - mn);
      float e2 = __builtin_amdgcn_exp2f(sc[c][2] - mn);
      float e3 = __builtin_amdgcn_exp2f(sc[c][3] - mn);
      rs0 += e0 + e1; rs1 += e2 + e3;
      *(uint2*)&P[w][lr][c*16 + lg*4] = make_uint2(pack2bf(e0,e1), pack2bf(e2,e3));
    }
    float rowsum = rs0 + rs1;
    rowsum += __shfl_xor(rowsum, 16);
    rowsum += __shfl_xor(rowsum, 32);
    lsum = lsum*alpha + rowsum;
    m = mn;

    // rescale O: Oacc[r] belongs to q=4lg+r; fetch that row's alpha
    float a0 = __shfl(alpha, lg*4 + 0);
    float a1 = __shfl(alpha, lg*4 + 1);
    float a2 = __shfl(alpha, lg*4 + 2);
    float a3 = __shfl(alpha, lg*4 + 3);
    Oacc[0] *= a0; Oacc[1] *= a1; Oacc[2] *= a2; Oacc[3] *= a3;

    __syncthreads();                             // Vt staged, P written
    #pragma unroll
    for (int u = 0; u < 2; ++u){
      short8 pf = *(const short8*)(&P[w][lr][lg*8 + u*32]);
      short8 vf = *(const short8*)(&Vt[lr][lg*8 + u*32]);
      Oacc = __builtin_amdgcn_mfma_f32_16x16x32_bf16(pf, vf, Oacc, 0, 0, 0);
    }
    #pragma unroll
    for (int c = 0; c < 4; ++c) kf[c] = kn[c];
    vv = vn;
  }

  float* Op = part + ((((size_t)sp*8 + bn)*4096) + qt*64 + w*16)*16;
  #pragma unroll
  for (int r = 0; r < 4; ++r)
    Op[(size_t)(lg*4 + r)*16 + lr] = Oacc[r];
  if (lg == 0){
    size_t mi = (((size_t)sp*8 + bn)*4096 + qt*64 + w*16 + lr)*2;
    ml[mi] = m; ml[mi+1] = lsum;
  }
}

// ---------------- K4: split-combine + out 1x1 conv + bias + residual ----------------
__global__ __launch_bounds__(256) void oproj_k(const float* __restrict__ part,
    const float* __restrict__ ml, const float* __restrict__ wo,
    const float* __restrict__ bo, const float* __restrict__ x,
    float* __restrict__ out){
  int b  = blockIdx.x >> 7;
  int s0 = (blockIdx.x & 127) * 32;
  __shared__ float A[64][33];
  __shared__ float W[4096];
  int t = threadIdx.x;
  for (int i = t; i < 1024; i += 256) ((float4*)W)[i] = ((const float4*)wo)[i];
  {
    int sl = t & 31;
    int nd = t >> 5;
    int n = nd >> 1, d0 = (nd & 1) * 8;
    int s = s0 + sl;
    size_t row = ((size_t)b*4 + n)*4096 + s;
    float mv[NSPLIT], lv[NSPLIT];
    #pragma unroll
    for (int sp = 0; sp < NSPLIT; ++sp){
      const float* mp = ml + ((size_t)sp*8*4096 + row)*2;
      mv[sp] = mp[0]; lv[sp] = mp[1];
    }
    float M = fmaxf(fmaxf(mv[0],mv[1]), fmaxf(mv[2],mv[3]));
    float L = 0.f, wv[NSPLIT];
    #pragma unroll
    for (int sp = 0; sp < NSPLIT; ++sp){
      wv[sp] = __builtin_amdgcn_exp2f(mv[sp] - M);
      L = fmaf(lv[sp], wv[sp], L);
    }
    float inv = __builtin_amdgcn_rcpf(L);
    float acc[8] = {0,0,0,0,0,0,0,0};
    #pragma unroll
    for (int sp = 0; sp < NSPLIT; ++sp){
      const float4* pp = (const float4*)(part + ((size_t)sp*8*4096 + row)*16 + d0);
      float4 u0 = pp[0], u1 = pp[1];
      acc[0]=fmaf(u0.x,wv[sp],acc[0]); acc[1]=fmaf(u0.y,wv[sp],acc[1]);
      acc[2]=fmaf(u0.z,wv[sp],acc[2]); acc[3]=fmaf(u0.w,wv[sp],acc[3]);
      acc[4]=fmaf(u1.x,wv[sp],acc[4]); acc[5]=fmaf(u1.y,wv[sp],acc[5]);
      acc[6]=fmaf(u1.z,wv[sp],acc[6]); acc[7]=fmaf(u1.w,wv[sp],acc[7]);
    }
    int c = n*16 + d0;
    #pragma unroll
    for (int j = 0; j < 8; ++j) A[c+j][sl] = acc[j]*inv;
  }
  __syncthreads();
  int sl = t & 31, grp = t >> 5;
  float acc[8];
  #pragma unroll
  for (int j = 0; j < 8; ++j) acc[j] = 0.f;
  for (int c = 0; c < 64; ++c){
    float a = A[c][sl];
    #pragma unroll
    for (int j = 0; j < 8; ++j) acc[j] = fmaf(W[(grp + j*8)*64 + c], a, acc[j]);
  }
  int s = s0 + sl;
  #pragma unroll
  for (int j = 0; j < 8; ++j){
    int o = grp + j*8;
    size_t idx = ((size_t)b*64 + o)*4096 + s;
    out[idx] = acc[j] + bo[o] + x[idx];
  }
}

extern "C" void kernel_launch(void* const* d_in, const int* in_sizes, int n_in,
                              void* d_out, int out_size, void* d_ws, size_t ws_size,
                              hipStream_t stream){
  const float* x   = (const float*)d_in[0];
  const float* gsc = (const float*)d_in[1];
  const float* gbi = (const float*)d_in[2];
  const float* wq  = (const float*)d_in[3];
  const float* wo  = (const float*)d_in[4];
  const float* bo  = (const float*)d_in[5];
  float* out = (float*)d_out;

  char* ws = (char*)d_ws;
  float* stats      = (float*)ws;                               // 512 B
  unsigned short* q = (unsigned short*)(ws + 1024);             // 1 MB
  unsigned short* k = (unsigned short*)(ws + 1024 + 1048576);   // 1 MB
  unsigned short* v = (unsigned short*)(ws + 1024 + 2097152);   // 1 MB
  float* part       = (float*)(ws + 1024 + 3145728);            // 8 MB
  float* ml         = (float*)(ws + 1024 + 3145728 + 8388608);  // 1 MB

  gn_stats_k<<<64,   256, 0, stream>>>(x, stats);
  qkv_k     <<<256,  256, 0, stream>>>(x, stats, gsc, gbi, wq, q, k, v);
  attn_k    <<<2048, 256, 0, stream>>>(q, k, v, part, ml);
  oproj_k   <<<256,  256, 0, stream>>>(part, ml, wo, bo, x, out);
}

// Round 3
// 70.090 us; speedup vs baseline: 2.5221x; 1.1034x over previous
//
#include <hip/hip_runtime.h>
#include <hip/hip_bf16.h>

typedef __attribute__((ext_vector_type(8))) short short8;
typedef __attribute__((ext_vector_type(4))) float f32x4;
typedef __attribute__((ext_vector_type(16))) float f32x16;
typedef __attribute__((ext_vector_type(4))) unsigned short ushort4v;
typedef __attribute__((ext_vector_type(4))) unsigned int uint4v;

#define DEV static __device__ __forceinline__

DEV unsigned short f2bf(float f){
  unsigned u = __float_as_uint(f);
  u += 0x7fffu + ((u >> 16) & 1u);
  return (unsigned short)(u >> 16);
}

DEV unsigned pack2bf(float a, float b){
  __hip_bfloat162 h = __float22bfloat162_rn(make_float2(a, b));
  unsigned u;
  __builtin_memcpy(&u, &h, 4);
  return u;
}

// B=2, C=64, H=W=64 -> S=4096, NH=4, HD=16, GROUPS=32
#define NSPLIT 4
#define KVCHUNK 1024
#define NT 16                    // KVCHUNK/64
#define QSCALE 0.180336880111f   // 0.125 * log2(e)

// ---------------- K1: GroupNorm partial sums (512 blocks = 64 groups x 8) ----------------
__global__ __launch_bounds__(256) void gn_partial_k(const float* __restrict__ x,
                                                    float* __restrict__ gp){
  int blk = blockIdx.x;
  float4 v = ((const float4*)(x + (size_t)blk*1024))[threadIdx.x];
  float s = v.x+v.y+v.z+v.w;
  float q = v.x*v.x+v.y*v.y+v.z*v.z+v.w*v.w;
  #pragma unroll
  for (int off = 1; off < 64; off <<= 1){
    s += __shfl_xor(s, off);
    q += __shfl_xor(q, off);
  }
  __shared__ float red[8];
  int w = threadIdx.x >> 6;
  if ((threadIdx.x & 63) == 0){ red[w*2] = s; red[w*2+1] = q; }
  __syncthreads();
  if (threadIdx.x == 0){
    gp[blk*2+0] = red[0]+red[2]+red[4]+red[6];
    gp[blk*2+1] = red[1]+red[3]+red[5]+red[7];
  }
}

// ---------------- K2: GN finalize + GN-apply + QKV 1x1 conv -> bf16 ----------------
// q,k,v: [bn][s][d=16]. q pre-scaled by 0.125*log2e.
__global__ __launch_bounds__(256) void qkv_k(const float* __restrict__ x,
    const float* __restrict__ gp, const float* __restrict__ gsc,
    const float* __restrict__ gbi, const float* __restrict__ wq,
    unsigned short* __restrict__ q, unsigned short* __restrict__ k,
    unsigned short* __restrict__ v){
  int b  = blockIdx.x >> 7;
  int s0 = (blockIdx.x & 127) * 32;
  __shared__ float W[192][68];    // padded: bank-conflict-free o-reads
  __shared__ float A[32][68];     // [s_local][c]
  __shared__ float MS[32][2];     // per-group mean, rstd
  int t = threadIdx.x;
  for (int i = t; i < 3072; i += 256){
    int o = i >> 4, c4 = (i & 15) * 4;
    *(float4*)&W[o][c4] = ((const float4*)wq)[i];
  }
  if (t < 32){
    float s = 0.f, ss = 0.f;
    #pragma unroll
    for (int i = 0; i < 8; ++i){
      const float* pp = gp + ((b*32 + t)*8 + i)*2;
      s += pp[0]; ss += pp[1];
    }
    float mean = s * (1.f/8192.f);
    MS[t][0] = mean;
    MS[t][1] = rsqrtf(ss * (1.f/8192.f) - mean*mean + 1e-5f);
  }
  __syncthreads();
  {
    int c  = t >> 2;
    int s8 = (t & 3) * 8;
    const float* px = x + ((size_t)b*64 + c)*4096 + s0 + s8;
    float4 v0 = *(const float4*)px;
    float4 v1 = *(const float4*)(px + 4);
    float sc = gsc[c] * MS[c>>1][1];
    float bi = gbi[c] - MS[c>>1][0] * sc;
    A[s8+0][c]=v0.x*sc+bi; A[s8+1][c]=v0.y*sc+bi; A[s8+2][c]=v0.z*sc+bi; A[s8+3][c]=v0.w*sc+bi;
    A[s8+4][c]=v1.x*sc+bi; A[s8+5][c]=v1.y*sc+bi; A[s8+6][c]=v1.z*sc+bi; A[s8+7][c]=v1.w*sc+bi;
  }
  __syncthreads();
  int sl = t >> 3, grp = t & 7;
  float acc[24];
  #pragma unroll
  for (int j = 0; j < 24; ++j) acc[j] = 0.f;
  for (int c4 = 0; c4 < 16; ++c4){
    float4 a = *(const float4*)&A[sl][c4*4];
    #pragma unroll
    for (int j = 0; j < 24; ++j){
      float4 wv = *(const float4*)&W[grp + j*8][c4*4];
      acc[j] = fmaf(a.x, wv.x, fmaf(a.y, wv.y, fmaf(a.z, wv.z, fmaf(a.w, wv.w, acc[j]))));
    }
  }
  int s = s0 + sl;
  #pragma unroll
  for (int j = 0; j < 24; ++j){
    int o = grp + j*8;
    int n = o / 48, r = o % 48;
    size_t base = (((size_t)b*4 + n)*4096 + s)*16;
    float val = acc[j];
    if (r < 16)       q[base + r]      = f2bf(val * QSCALE);
    else if (r < 32)  k[base + r - 16] = f2bf(val);
    else              v[base + r - 32] = f2bf(val);
  }
}

// ---------------- K3: flash attention, 32x32x16 MFMA, in-lane softmax ----------------
// grid 1024 = bn(8) x sp(4) x qt(32); 4 waves/block; wave w: q rows qt*128+w*32..+31
__global__ __launch_bounds__(256) void attn_k(const unsigned short* __restrict__ qb,
    const unsigned short* __restrict__ kb, const unsigned short* __restrict__ vb,
    float* __restrict__ part, float* __restrict__ ml){
  int blk = blockIdx.x;
  int qt = blk & 31;
  int sp = (blk >> 5) & (NSPLIT-1);
  int bn = blk >> 7;
  int t = threadIdx.x, w = t >> 6, l = t & 63;
  int lq = l & 31, hi = l >> 5;

  const unsigned short* Kp = kb + ((size_t)bn*4096 + sp*KVCHUNK)*16;
  const unsigned short* Vp = vb + ((size_t)bn*4096 + sp*KVCHUNK)*16;
  int qrow = qt*128 + w*32;
  const unsigned short* Qp = qb + ((size_t)bn*4096 + qrow)*16;

  __shared__ alignas(16) unsigned short Vt[2][16][72];   // V^T double-buffered

  // Q as B-frag: lane holds Q[q=lq][d=8hi+j]
  short8 qf = *(const short8*)(Qp + (size_t)lq*16 + hi*8);

  f32x16 O;
  #pragma unroll
  for (int r = 0; r < 16; ++r) O[r] = 0.f;
  f32x16 zero = O;
  float m = -__builtin_inff(), lsum = 0.f;

  int skv = t >> 2, sd = (t & 3) * 4;                    // V staging indices
  const unsigned short* vsrc = Vp + (size_t)skv*16 + sd;
  const unsigned short* kaddr = Kp + (size_t)lq*16 + hi*8;

  // prologue: tile 0
  short8 kf0 = *(const short8*)(kaddr);
  short8 kf1 = *(const short8*)(kaddr + 512);
  {
    ushort4v vv = *(const ushort4v*)(vsrc);
    Vt[0][sd+0][skv]=vv[0]; Vt[0][sd+1][skv]=vv[1];
    Vt[0][sd+2][skv]=vv[2]; Vt[0][sd+3][skv]=vv[3];
  }

  for (int kt = 0; kt < NT; ++kt){
    __syncthreads();                      // Vt[cur] staged; prev reads of Vt[cur^1] done
    int cur = kt & 1;
    bool pf = (kt + 1) < NT;
    short8 kn0 = {}, kn1 = {};
    ushort4v vn = {};
    if (pf){
      const unsigned short* ka = kaddr + (size_t)(kt+1)*1024;
      kn0 = *(const short8*)(ka);
      kn1 = *(const short8*)(ka + 512);
      vn  = *(const ushort4v*)(vsrc + (size_t)(kt+1)*1024);
    }

    // S^T = K Q^T : lane holds S[kv][q=lq], kv = 64kt + 32c + (r&3)+8(r>>2)+4hi
    f32x16 sA = __builtin_amdgcn_mfma_f32_32x32x16_bf16(kf0, qf, zero, 0, 0, 0);
    f32x16 sB = __builtin_amdgcn_mfma_f32_32x32x16_bf16(kf1, qf, zero, 0, 0, 0);

    // tile max (in-lane tree + 1 cross-shuffle)
    float mx = sA[0];
    #pragma unroll
    for (int r = 1; r < 16; ++r) mx = fmaxf(mx, sA[r]);
    #pragma unroll
    for (int r = 0; r < 16; ++r) mx = fmaxf(mx, sB[r]);
    mx = fmaxf(mx, __shfl_xor(mx, 32));

    // defer-max rescale (rare, wave-uniform)
    if (__any(mx > m + 8.f)){
      float mn = fmaxf(m, mx);
      float al = __builtin_amdgcn_exp2f(m - mn);   // first tile: exp2(-inf)=0
      lsum *= al;
      m = mn;
      #pragma unroll
      for (int r = 0; r < 16; ++r){
        int qr = (r&3) + 8*(r>>2) + 4*hi;
        O[r] *= __shfl(al, qr);
      }
    }

    // exp2 + in-lane partial rowsum (partner lane holds the other half of the row)
    #pragma unroll
    for (int r = 0; r < 16; ++r){ sA[r] = __builtin_amdgcn_exp2f(sA[r] - m); lsum += sA[r]; }
    #pragma unroll
    for (int r = 0; r < 16; ++r){ sB[r] = __builtin_amdgcn_exp2f(sB[r] - m); lsum += sB[r]; }

    // PV: 4 steps of K=16; A-frag assembled in-register (cvt_pk + 2 shuffles)
    #pragma unroll
    for (int s = 0; s < 4; ++s){
      const f32x16& pc = (s < 2) ? sA : sB;
      const int h = s & 1;
      unsigned X0 = pack2bf(pc[8*h+0], pc[8*h+1]);
      unsigned X1 = pack2bf(pc[8*h+2], pc[8*h+3]);
      unsigned Y0 = pack2bf(pc[8*h+4], pc[8*h+5]);
      unsigned Y1 = pack2bf(pc[8*h+6], pc[8*h+7]);
      unsigned e0 = (unsigned)__shfl_xor((int)(hi ? X0 : Y0), 32);
      unsigned e1 = (unsigned)__shfl_xor((int)(hi ? X1 : Y1), 32);
      uint4v pw;
      pw[0] = hi ? e0 : X0; pw[1] = hi ? e1 : X1;
      pw[2] = hi ? Y0 : e0; pw[3] = hi ? Y1 : e1;
      short8 pa = __builtin_bit_cast(short8, pw);
      short8 vf = {};
      if (lq < 16) vf = *(const short8*)(&Vt[cur][lq][s*16 + hi*8]);
      O = __builtin_amdgcn_mfma_f32_32x32x16_bf16(pa, vf, O, 0, 0, 0);
    }

    if (pf){
      Vt[cur^1][sd+0][skv]=vn[0]; Vt[cur^1][sd+1][skv]=vn[1];
      Vt[cur^1][sd+2][skv]=vn[2]; Vt[cur^1][sd+3][skv]=vn[3];
      kf0 = kn0; kf1 = kn1;
    }
  }

  lsum += __shfl_xor(lsum, 32);
  float* Op = part + (((size_t)sp*8 + bn)*4096 + qrow)*16;
  #pragma unroll
  for (int r = 0; r < 16; ++r){
    int qr = (r&3) + 8*(r>>2) + 4*hi;
    if (lq < 16) Op[(size_t)qr*16 + lq] = O[r];
  }
  if (l < 32){
    size_t mi = ((size_t)sp*8 + bn)*4096 + qrow + lq;
    ml[mi*2+0] = m; ml[mi*2+1] = lsum;
  }
}

// ---------------- K4: split-combine + out 1x1 conv + bias + residual ----------------
// grid 512 = b(2) x s-tile(256 of 16)
__global__ __launch_bounds__(256) void oproj_k(const float* __restrict__ part,
    const float* __restrict__ ml, const float* __restrict__ wo,
    const float* __restrict__ bo, const float* __restrict__ x,
    float* __restrict__ out){
  int b  = blockIdx.x >> 8;
  int s0 = (blockIdx.x & 255) * 16;
  __shared__ float W[64][68];
  __shared__ float A[16][68];     // [s_local][c]
  int t = threadIdx.x;
  for (int i = t; i < 1024; i += 256){
    int o = i >> 4, c4 = (i & 15) * 4;
    *(float4*)&W[o][c4] = ((const float4*)wo)[i];
  }
  {
    int sl = t & 15;
    int u  = t >> 4;
    int n = u >> 2, d4 = (u & 3) * 4;
    size_t row = ((size_t)b*4 + n)*4096 + s0 + sl;
    float mv[NSPLIT], lv[NSPLIT];
    #pragma unroll
    for (int sp = 0; sp < NSPLIT; ++sp){
      const float* mp = ml + ((size_t)sp*8*4096 + row)*2;
      mv[sp] = mp[0]; lv[sp] = mp[1];
    }
    float M = fmaxf(fmaxf(mv[0],mv[1]), fmaxf(mv[2],mv[3]));
    float L = 0.f, wv[NSPLIT];
    #pragma unroll
    for (int sp = 0; sp < NSPLIT; ++sp){
      wv[sp] = __builtin_amdgcn_exp2f(mv[sp] - M);
      L = fmaf(lv[sp], wv[sp], L);
    }
    float inv = 1.f / L;
    float4 acc = {0.f,0.f,0.f,0.f};
    #pragma unroll
    for (int sp = 0; sp < NSPLIT; ++sp){
      float4 u0 = *(const float4*)(part + ((size_t)sp*8*4096 + row)*16 + d4);
      acc.x = fmaf(u0.x, wv[sp], acc.x); acc.y = fmaf(u0.y, wv[sp], acc.y);
      acc.z = fmaf(u0.z, wv[sp], acc.z); acc.w = fmaf(u0.w, wv[sp], acc.w);
    }
    acc.x *= inv; acc.y *= inv; acc.z *= inv; acc.w *= inv;
    *(float4*)&A[sl][n*16 + d4] = acc;
  }
  __syncthreads();
  int sl = t & 15, grp = t >> 4;
  float acc[4] = {0.f,0.f,0.f,0.f};
  for (int c4 = 0; c4 < 16; ++c4){
    float4 a = *(const float4*)&A[sl][c4*4];
    #pragma unroll
    for (int j = 0; j < 4; ++j){
      float4 wv = *(const float4*)&W[grp + j*16][c4*4];
      acc[j] = fmaf(a.x, wv.x, fmaf(a.y, wv.y, fmaf(a.z, wv.z, fmaf(a.w, wv.w, acc[j]))));
    }
  }
  int s = s0 + sl;
  #pragma unroll
  for (int j = 0; j < 4; ++j){
    int o = grp + j*16;
    size_t idx = ((size_t)b*64 + o)*4096 + s;
    out[idx] = acc[j] + bo[o] + x[idx];
  }
}

extern "C" void kernel_launch(void* const* d_in, const int* in_sizes, int n_in,
                              void* d_out, int out_size, void* d_ws, size_t ws_size,
                              hipStream_t stream){
  const float* x   = (const float*)d_in[0];
  const float* gsc = (const float*)d_in[1];
  const float* gbi = (const float*)d_in[2];
  const float* wq  = (const float*)d_in[3];
  const float* wo  = (const float*)d_in[4];
  const float* bo  = (const float*)d_in[5];
  float* out = (float*)d_out;

  char* ws = (char*)d_ws;
  float* gp         = (float*)ws;                                   // 4 KB
  unsigned short* q = (unsigned short*)(ws + 8192);                 // 1 MB
  unsigned short* k = (unsigned short*)(ws + 8192 + 1048576);       // 1 MB
  unsigned short* v = (unsigned short*)(ws + 8192 + 2097152);       // 1 MB
  float* part       = (float*)(ws + 8192 + 3145728);                // 8 MB
  float* ml         = (float*)(ws + 8192 + 3145728 + 8388608);      // 1 MB

  gn_partial_k<<<512,  256, 0, stream>>>(x, gp);
  qkv_k       <<<256,  256, 0, stream>>>(x, gp, gsc, gbi, wq, q, k, v);
  attn_k      <<<1024, 256, 0, stream>>>(q, k, v, part, ml);
  oproj_k     <<<512,  256, 0, stream>>>(part, ml, wo, bo, x, out);
}

// Round 4
// 61.710 us; speedup vs baseline: 2.8646x; 1.1358x over previous
//
#include <hip/hip_runtime.h>
#include <hip/hip_bf16.h>

typedef __attribute__((ext_vector_type(8))) short short8;
typedef __attribute__((ext_vector_type(4))) float f32x4;
typedef __attribute__((ext_vector_type(16))) float f32x16;
typedef __attribute__((ext_vector_type(4))) unsigned short ushort4v;
typedef __attribute__((ext_vector_type(4))) unsigned int uint4v;

#define DEV static __device__ __forceinline__

DEV unsigned short f2bf(float f){
  unsigned u = __float_as_uint(f);
  u += 0x7fffu + ((u >> 16) & 1u);
  return (unsigned short)(u >> 16);
}

DEV unsigned pack2bf(float a, float b){
  __hip_bfloat162 h = __float22bfloat162_rn(make_float2(a, b));
  unsigned u;
  __builtin_memcpy(&u, &h, 4);
  return u;
}

// B=2, C=64, H=W=64 -> S=4096, NH=4, HD=16, GROUPS=32
#define QSCALE 0.180336880111f   // 0.125 * log2(e); softmax in exp2 domain, max-free

// ---------------- K1: GroupNorm partial sums (512 blocks = 64 groups x 8) ----------------
__global__ __launch_bounds__(256) void gn_partial_k(const float* __restrict__ x,
                                                    float* __restrict__ gp){
  int blk = blockIdx.x;
  float4 v = ((const float4*)(x + (size_t)blk*1024))[threadIdx.x];
  float s = v.x+v.y+v.z+v.w;
  float q = v.x*v.x+v.y*v.y+v.z*v.z+v.w*v.w;
  #pragma unroll
  for (int off = 1; off < 64; off <<= 1){
    s += __shfl_xor(s, off);
    q += __shfl_xor(q, off);
  }
  __shared__ float red[8];
  int w = threadIdx.x >> 6;
  if ((threadIdx.x & 63) == 0){ red[w*2] = s; red[w*2+1] = q; }
  __syncthreads();
  if (threadIdx.x == 0){
    gp[blk*2+0] = red[0]+red[2]+red[4]+red[6];
    gp[blk*2+1] = red[1]+red[3]+red[5]+red[7];
  }
}

// ---------------- K2: GN finalize + GN-apply + QKV 1x1 conv -> bf16 ----------------
// q,k,v: [bn][s][d=16]. q pre-scaled by 0.125*log2e.
__global__ __launch_bounds__(256) void qkv_k(const float* __restrict__ x,
    const float* __restrict__ gp, const float* __restrict__ gsc,
    const float* __restrict__ gbi, const float* __restrict__ wq,
    unsigned short* __restrict__ q, unsigned short* __restrict__ k,
    unsigned short* __restrict__ v){
  int b  = blockIdx.x >> 7;
  int s0 = (blockIdx.x & 127) * 32;
  __shared__ float W[192][68];    // padded: bank-conflict-free o-reads
  __shared__ float A[32][68];     // [s_local][c]
  __shared__ float MS[32][2];     // per-group mean, rstd
  int t = threadIdx.x;
  for (int i = t; i < 3072; i += 256){
    int o = i >> 4, c4 = (i & 15) * 4;
    *(float4*)&W[o][c4] = ((const float4*)wq)[i];
  }
  if (t < 32){
    float s = 0.f, ss = 0.f;
    #pragma unroll
    for (int i = 0; i < 8; ++i){
      const float* pp = gp + ((b*32 + t)*8 + i)*2;
      s += pp[0]; ss += pp[1];
    }
    float mean = s * (1.f/8192.f);
    MS[t][0] = mean;
    MS[t][1] = rsqrtf(ss * (1.f/8192.f) - mean*mean + 1e-5f);
  }
  __syncthreads();
  {
    int c  = t >> 2;
    int s8 = (t & 3) * 8;
    const float* px = x + ((size_t)b*64 + c)*4096 + s0 + s8;
    float4 v0 = *(const float4*)px;
    float4 v1 = *(const float4*)(px + 4);
    float sc = gsc[c] * MS[c>>1][1];
    float bi = gbi[c] - MS[c>>1][0] * sc;
    A[s8+0][c]=v0.x*sc+bi; A[s8+1][c]=v0.y*sc+bi; A[s8+2][c]=v0.z*sc+bi; A[s8+3][c]=v0.w*sc+bi;
    A[s8+4][c]=v1.x*sc+bi; A[s8+5][c]=v1.y*sc+bi; A[s8+6][c]=v1.z*sc+bi; A[s8+7][c]=v1.w*sc+bi;
  }
  __syncthreads();
  int sl = t >> 3, grp = t & 7;
  float acc[24];
  #pragma unroll
  for (int j = 0; j < 24; ++j) acc[j] = 0.f;
  for (int c4 = 0; c4 < 16; ++c4){
    float4 a = *(const float4*)&A[sl][c4*4];
    #pragma unroll
    for (int j = 0; j < 24; ++j){
      float4 wv = *(const float4*)&W[grp + j*8][c4*4];
      acc[j] = fmaf(a.x, wv.x, fmaf(a.y, wv.y, fmaf(a.z, wv.z, fmaf(a.w, wv.w, acc[j]))));
    }
  }
  int s = s0 + sl;
  #pragma unroll
  for (int j = 0; j < 24; ++j){
    int o = grp + j*8;
    int n = o / 48, r = o % 48;
    size_t base = (((size_t)b*4 + n)*4096 + s)*16;
    float val = acc[j];
    if (r < 16)       q[base + r]      = f2bf(val * QSCALE);
    else if (r < 32)  k[base + r - 16] = f2bf(val);
    else              v[base + r - 32] = f2bf(val);
  }
}

// ---------------- K3: flash attention, 32x32x16 MFMA, max-free softmax ----------------
// grid = bn(8) x sp(2^LNSP) x qt(32); 4 waves/block; wave w: q rows qt*128+w*32..+31
// lsum accumulated inside the PV MFMA via a ones-column (B col 16).
// PV A-frags are the lane's own S registers (KV column-permuted V^T staging).
template<int LNSP>
__global__ __launch_bounds__(256) void attn_k(const unsigned short* __restrict__ qb,
    const unsigned short* __restrict__ kb, const unsigned short* __restrict__ vb,
    float* __restrict__ part, float* __restrict__ lsums){
  constexpr int NSP = 1 << LNSP;
  constexpr int NT  = 64 >> LNSP;          // 64-row KV tiles per split
  int blk = blockIdx.x;
  int qt = blk & 31;
  int sp = (blk >> 5) & (NSP - 1);
  int bn = blk >> (5 + LNSP);
  int t = threadIdx.x, w = t >> 6, l = t & 63;
  int lq = l & 31, hi = l >> 5;

  const unsigned short* Kp = kb + ((size_t)bn*4096 + sp*(NT*64))*16;
  const unsigned short* Vp = vb + ((size_t)bn*4096 + sp*(NT*64))*16;
  int qrow = qt*128 + w*32;
  const unsigned short* Qp = qb + ((size_t)bn*4096 + qrow)*16;

  __shared__ alignas(16) unsigned short Vt[2][16][72];   // V^T, KV-permuted cols, dbuf

  // Q as B-frag: lane holds Q[q=lq][d=8hi+j]
  short8 qf = *(const short8*)(Qp + (size_t)lq*16 + hi*8);

  f32x16 O, zero;
  #pragma unroll
  for (int r = 0; r < 16; ++r){ O[r] = 0.f; zero[r] = 0.f; }

  short8 vones;
  #pragma unroll
  for (int r = 0; r < 8; ++r) vones[r] = (short)0x3F80;  // bf16 1.0

  // V staging: thread handles kv row skv, d cols sd..sd+3; store at permuted column
  int skv = t >> 2, sd = (t & 3) * 4;
  int xk = skv & 15;
  int scol = (skv & 48) + (xk & 3) + (((xk >> 2) & 1) << 3) + (((xk >> 3) & 1) << 2);
  const unsigned short* vsrc = Vp + (size_t)skv*16 + sd;
  const unsigned short* kaddr = Kp + (size_t)lq*16 + hi*8;

  // prologue: tile 0
  short8 kf0 = *(const short8*)(kaddr);
  short8 kf1 = *(const short8*)(kaddr + 512);
  {
    ushort4v vv = *(const ushort4v*)(vsrc);
    Vt[0][sd+0][scol]=vv[0]; Vt[0][sd+1][scol]=vv[1];
    Vt[0][sd+2][scol]=vv[2]; Vt[0][sd+3][scol]=vv[3];
  }

  for (int kt = 0; kt < NT; ++kt){
    __syncthreads();                      // Vt[cur] staged; prev reads of Vt[cur^1] done
    int cur = kt & 1;
    bool pf = (kt + 1) < NT;
    short8 kn0 = {}, kn1 = {};
    ushort4v vn = {};
    if (pf){
      const unsigned short* ka = kaddr + (size_t)(kt+1)*1024;
      kn0 = *(const short8*)(ka);
      kn1 = *(const short8*)(ka + 512);
      vn  = *(const ushort4v*)(vsrc + (size_t)(kt+1)*1024);
    }

    // S^T = K Q^T : lane holds S[kv][q=lq], kv = 64kt + 32c + (r&3)+8(r>>2)+4hi
    f32x16 sA = __builtin_amdgcn_mfma_f32_32x32x16_bf16(kf0, qf, zero, 0, 0, 0);
    f32x16 sB = __builtin_amdgcn_mfma_f32_32x32x16_bf16(kf1, qf, zero, 0, 0, 0);

    // max-free softmax: P = exp2(S) directly (|S| << exp2 overflow range)
    #pragma unroll
    for (int r = 0; r < 16; ++r) sA[r] = __builtin_amdgcn_exp2f(sA[r]);
    #pragma unroll
    for (int r = 0; r < 16; ++r) sB[r] = __builtin_amdgcn_exp2f(sB[r]);

    // PV: 4 K=16 steps; A-frag = lane's own 8 P-regs (cvt_pk only, no shuffles)
    auto pvstep = [&](const f32x16& pc, int h8, int vcol){
      uint4v pw;
      pw[0] = pack2bf(pc[h8+0], pc[h8+1]);
      pw[1] = pack2bf(pc[h8+2], pc[h8+3]);
      pw[2] = pack2bf(pc[h8+4], pc[h8+5]);
      pw[3] = pack2bf(pc[h8+6], pc[h8+7]);
      short8 pa = __builtin_bit_cast(short8, pw);
      short8 vf = {};
      if (lq < 16)       vf = *(const short8*)(&Vt[cur][lq][vcol + hi*8]);
      else if (lq == 16) vf = vones;            // lsum column
      O = __builtin_amdgcn_mfma_f32_32x32x16_bf16(pa, vf, O, 0, 0, 0);
    };
    pvstep(sA, 0, 0);
    pvstep(sA, 8, 16);
    pvstep(sB, 0, 32);
    pvstep(sB, 8, 48);

    if (pf){
      Vt[cur^1][sd+0][scol]=vn[0]; Vt[cur^1][sd+1][scol]=vn[1];
      Vt[cur^1][sd+2][scol]=vn[2]; Vt[cur^1][sd+3][scol]=vn[3];
      kf0 = kn0; kf1 = kn1;
    }
  }

  // D[row=q][col]: col=lq (d for lq<16, lsum at col 16); row=(r&3)+8(r>>2)+4hi
  float* Op = part + (((size_t)sp*8 + bn)*4096 + qrow)*16;
  size_t lbase = ((size_t)sp*8 + bn)*4096 + qrow;
  #pragma unroll
  for (int r = 0; r < 16; ++r){
    int qr = (r&3) + 8*(r>>2) + 4*hi;
    if (lq < 16) Op[(size_t)qr*16 + lq] = O[r];
  }
  if (lq == 16){
    #pragma unroll
    for (int r = 0; r < 16; ++r){
      int qr = (r&3) + 8*(r>>2) + 4*hi;
      lsums[lbase + qr] = O[r];
    }
  }
}

// ---------------- K4: split-combine (plain sums) + out 1x1 conv + bias + residual ----------------
// grid 512 = b(2) x s-tile(256 of 16)
__global__ __launch_bounds__(256) void oproj_k(const float* __restrict__ part,
    const float* __restrict__ lsums, const float* __restrict__ wo,
    const float* __restrict__ bo, const float* __restrict__ x,
    float* __restrict__ out, int nsplit){
  int b  = blockIdx.x >> 8;
  int s0 = (blockIdx.x & 255) * 16;
  __shared__ float W[64][68];
  __shared__ float A[16][68];     // [s_local][c]
  int t = threadIdx.x;
  for (int i = t; i < 1024; i += 256){
    int o = i >> 4, c4 = (i & 15) * 4;
    *(float4*)&W[o][c4] = ((const float4*)wo)[i];
  }
  {
    int sl = t & 15;
    int u  = t >> 4;
    int n = u >> 2, d4 = (u & 3) * 4;
    size_t row = ((size_t)b*4 + n)*4096 + s0 + sl;
    float L = 0.f;
    for (int sp = 0; sp < nsplit; ++sp) L += lsums[(size_t)sp*32768 + row];
    float4 acc = {0.f,0.f,0.f,0.f};
    for (int sp = 0; sp < nsplit; ++sp){
      float4 u0 = *(const float4*)(part + ((size_t)sp*32768 + row)*16 + d4);
      acc.x += u0.x; acc.y += u0.y; acc.z += u0.z; acc.w += u0.w;
    }
    float inv = 1.f / L;
    acc.x *= inv; acc.y *= inv; acc.z *= inv; acc.w *= inv;
    *(float4*)&A[sl][n*16 + d4] = acc;
  }
  __syncthreads();
  int sl = t & 15, grp = t >> 4;
  float acc[4] = {0.f,0.f,0.f,0.f};
  for (int c4 = 0; c4 < 16; ++c4){
    float4 a = *(const float4*)&A[sl][c4*4];
    #pragma unroll
    for (int j = 0; j < 4; ++j){
      float4 wv = *(const float4*)&W[grp + j*16][c4*4];
      acc[j] = fmaf(a.x, wv.x, fmaf(a.y, wv.y, fmaf(a.z, wv.z, fmaf(a.w, wv.w, acc[j]))));
    }
  }
  int s = s0 + sl;
  #pragma unroll
  for (int j = 0; j < 4; ++j){
    int o = grp + j*16;
    size_t idx = ((size_t)b*64 + o)*4096 + s;
    out[idx] = acc[j] + bo[o] + x[idx];
  }
}

extern "C" void kernel_launch(void* const* d_in, const int* in_sizes, int n_in,
                              void* d_out, int out_size, void* d_ws, size_t ws_size,
                              hipStream_t stream){
  const float* x   = (const float*)d_in[0];
  const float* gsc = (const float*)d_in[1];
  const float* gbi = (const float*)d_in[2];
  const float* wq  = (const float*)d_in[3];
  const float* wo  = (const float*)d_in[4];
  const float* bo  = (const float*)d_in[5];
  float* out = (float*)d_out;

  char* ws = (char*)d_ws;
  float* gp         = (float*)ws;                                   // 4 KB
  unsigned short* q = (unsigned short*)(ws + 8192);                 // 1 MB
  unsigned short* k = (unsigned short*)(ws + 8192 + 1048576);       // 1 MB
  unsigned short* v = (unsigned short*)(ws + 8192 + 2097152);       // 1 MB
  float* part       = (float*)(ws + 8192 + 3145728);                // nsplit*2 MB

  // part: nsplit*2MB ; lsums: nsplit*128KB
  size_t need8 = 8192 + 3145728 + 8u*2097152 + 8u*131072;
  bool big = ws_size >= need8;
  int nsplit = big ? 8 : 4;
  float* lsums = (float*)(ws + 8192 + 3145728 + (size_t)nsplit*2097152);

  gn_partial_k<<<512,  256, 0, stream>>>(x, gp);
  qkv_k       <<<256,  256, 0, stream>>>(x, gp, gsc, gbi, wq, q, k, v);
  if (big) attn_k<3><<<2048, 256, 0, stream>>>(q, k, v, part, lsums);
  else     attn_k<2><<<1024, 256, 0, stream>>>(q, k, v, part, lsums);
  oproj_k     <<<512,  256, 0, stream>>>(part, lsums, wo, bo, x, out, nsplit);
}

// Round 5
// 60.695 us; speedup vs baseline: 2.9125x; 1.0167x over previous
//
#include <hip/hip_runtime.h>
#include <hip/hip_bf16.h>

typedef __attribute__((ext_vector_type(8))) short short8;
typedef __attribute__((ext_vector_type(4))) float f32x4;
typedef __attribute__((ext_vector_type(16))) float f32x16;
typedef __attribute__((ext_vector_type(4))) unsigned short ushort4v;
typedef __attribute__((ext_vector_type(4))) unsigned int uint4v;

#define DEV static __device__ __forceinline__

DEV unsigned short f2bf(float f){
  unsigned u = __float_as_uint(f);
  u += 0x7fffu + ((u >> 16) & 1u);
  return (unsigned short)(u >> 16);
}

DEV unsigned pack2bf(float a, float b){
  __hip_bfloat162 h = __float22bfloat162_rn(make_float2(a, b));
  unsigned u;
  __builtin_memcpy(&u, &h, 4);
  return u;
}

// B=2, C=64, H=W=64 -> S=4096, NH=4, HD=16, GROUPS=32
#define QSCALE 0.180336880111f   // 0.125 * log2(e); softmax in exp2 domain, max-free

// ---------------- K1: GroupNorm partial sums (512 blocks = 64 groups x 8) ----------------
__global__ __launch_bounds__(256) void gn_partial_k(const float* __restrict__ x,
                                                    float* __restrict__ gp){
  int blk = blockIdx.x;
  float4 v = ((const float4*)(x + (size_t)blk*1024))[threadIdx.x];
  float s = v.x+v.y+v.z+v.w;
  float q = v.x*v.x+v.y*v.y+v.z*v.z+v.w*v.w;
  #pragma unroll
  for (int off = 1; off < 64; off <<= 1){
    s += __shfl_xor(s, off);
    q += __shfl_xor(q, off);
  }
  __shared__ float red[8];
  int w = threadIdx.x >> 6;
  if ((threadIdx.x & 63) == 0){ red[w*2] = s; red[w*2+1] = q; }
  __syncthreads();
  if (threadIdx.x == 0){
    gp[blk*2+0] = red[0]+red[2]+red[4]+red[6];
    gp[blk*2+1] = red[1]+red[3]+red[5]+red[7];
  }
}

// ---------------- K2: GN finalize + GN-apply + QKV 1x1 conv -> bf16 ----------------
// q,k,v: [bn][s][d=16]. q pre-scaled by 0.125*log2e.
__global__ __launch_bounds__(256) void qkv_k(const float* __restrict__ x,
    const float* __restrict__ gp, const float* __restrict__ gsc,
    const float* __restrict__ gbi, const float* __restrict__ wq,
    unsigned short* __restrict__ q, unsigned short* __restrict__ k,
    unsigned short* __restrict__ v){
  int b  = blockIdx.x >> 7;
  int s0 = (blockIdx.x & 127) * 32;
  __shared__ float W[192][68];    // padded: bank-conflict-free o-reads
  __shared__ float A[32][68];     // [s_local][c]
  __shared__ float MS[32][2];     // per-group mean, rstd
  int t = threadIdx.x;
  for (int i = t; i < 3072; i += 256){
    int o = i >> 4, c4 = (i & 15) * 4;
    *(float4*)&W[o][c4] = ((const float4*)wq)[i];
  }
  if (t < 32){
    float s = 0.f, ss = 0.f;
    #pragma unroll
    for (int i = 0; i < 8; ++i){
      const float* pp = gp + ((b*32 + t)*8 + i)*2;
      s += pp[0]; ss += pp[1];
    }
    float mean = s * (1.f/8192.f);
    MS[t][0] = mean;
    MS[t][1] = rsqrtf(ss * (1.f/8192.f) - mean*mean + 1e-5f);
  }
  __syncthreads();
  {
    int c  = t >> 2;
    int s8 = (t & 3) * 8;
    const float* px = x + ((size_t)b*64 + c)*4096 + s0 + s8;
    float4 v0 = *(const float4*)px;
    float4 v1 = *(const float4*)(px + 4);
    float sc = gsc[c] * MS[c>>1][1];
    float bi = gbi[c] - MS[c>>1][0] * sc;
    A[s8+0][c]=v0.x*sc+bi; A[s8+1][c]=v0.y*sc+bi; A[s8+2][c]=v0.z*sc+bi; A[s8+3][c]=v0.w*sc+bi;
    A[s8+4][c]=v1.x*sc+bi; A[s8+5][c]=v1.y*sc+bi; A[s8+6][c]=v1.z*sc+bi; A[s8+7][c]=v1.w*sc+bi;
  }
  __syncthreads();
  int sl = t >> 3, grp = t & 7;
  float acc[24];
  #pragma unroll
  for (int j = 0; j < 24; ++j) acc[j] = 0.f;
  for (int c4 = 0; c4 < 16; ++c4){
    float4 a = *(const float4*)&A[sl][c4*4];
    #pragma unroll
    for (int j = 0; j < 24; ++j){
      float4 wv = *(const float4*)&W[grp + j*8][c4*4];
      acc[j] = fmaf(a.x, wv.x, fmaf(a.y, wv.y, fmaf(a.z, wv.z, fmaf(a.w, wv.w, acc[j]))));
    }
  }
  int s = s0 + sl;
  #pragma unroll
  for (int j = 0; j < 24; ++j){
    int o = grp + j*8;
    int n = o / 48, r = o % 48;
    size_t base = (((size_t)b*4 + n)*4096 + s)*16;
    float val = acc[j];
    if (r < 16)       q[base + r]      = f2bf(val * QSCALE);
    else if (r < 32)  k[base + r - 16] = f2bf(val);
    else              v[base + r - 32] = f2bf(val);
  }
}

// ---------------- K3: flash attention, 32x32x16 MFMA, max-free softmax ----------------
// grid = qt(32) x sp(2^LNSP) x bn(8), bn = blk&7 (XCD-local K/V working set).
// 4 waves/block; wave w: q rows qt*128+w*32..+31.
// lsum accumulated inside the PV MFMA via a constant ones-row (Vt row 16).
// PV A-frags are the lane's own S registers (KV column-permuted V^T staging).
template<int LNSP>
__global__ __launch_bounds__(256) void attn_k(const unsigned short* __restrict__ qb,
    const unsigned short* __restrict__ kb, const unsigned short* __restrict__ vb,
    float* __restrict__ part, float* __restrict__ lsums){
  constexpr int NSP = 1 << LNSP;
  constexpr int NT  = 64 >> LNSP;          // 64-row KV tiles per split
  int blk = blockIdx.x;
  int bn = blk & 7;                        // XCD-locality: one bn per XCD
  int sp = (blk >> 3) & (NSP - 1);
  int qt = blk >> (3 + LNSP);
  int t = threadIdx.x, w = t >> 6, l = t & 63;
  int lq = l & 31, hi = l >> 5;

  const unsigned short* Kp = kb + ((size_t)bn*4096 + sp*(NT*64))*16;
  const unsigned short* Vp = vb + ((size_t)bn*4096 + sp*(NT*64))*16;
  int qrow = qt*128 + w*32;
  const unsigned short* Qp = qb + ((size_t)bn*4096 + qrow)*16;

  // V^T tiles, KV-permuted cols, double-buffered. Rows 0-15: V^T (restaged per
  // tile); row 16: constant bf16 1.0 (lsum column); rows 17-31: constant 0.
  __shared__ alignas(16) unsigned short Vt[2][32][72];
  for (int i = t; i < 2304; i += 256){     // 2 bufs x 16 const rows x 72
    int buf = (i >= 1152);
    int ii  = buf ? i - 1152 : i;
    int row = 16 + ii / 72, col = ii % 72;
    Vt[buf][row][col] = (row == 16) ? (unsigned short)0x3F80 : (unsigned short)0;
  }

  // Q as B-frag: lane holds Q[q=lq][d=8hi+j]
  short8 qf = *(const short8*)(Qp + (size_t)lq*16 + hi*8);

  f32x16 O, zero;
  #pragma unroll
  for (int r = 0; r < 16; ++r){ O[r] = 0.f; zero[r] = 0.f; }

  // V staging: thread handles kv row skv, d cols sd..sd+3; store at permuted column
  int skv = t >> 2, sd = (t & 3) * 4;
  int xk = skv & 15;
  int scol = (skv & 48) + (xk & 3) + (((xk >> 2) & 1) << 3) + (((xk >> 3) & 1) << 2);
  const unsigned short* vsrc = Vp + (size_t)skv*16 + sd;
  const unsigned short* kaddr = Kp + (size_t)lq*16 + hi*8;

  // prologue: tile 0 loads
  short8 kf0 = *(const short8*)(kaddr);
  short8 kf1 = *(const short8*)(kaddr + 512);
  ushort4v vv = *(const ushort4v*)(vsrc);

  for (int kt = 0; kt < NT; ++kt){
    int cur = kt & 1;
    // stage V tile kt (loaded a full tile ago) -> Vt[cur]
    Vt[cur][sd+0][scol]=vv[0]; Vt[cur][sd+1][scol]=vv[1];
    Vt[cur][sd+2][scol]=vv[2]; Vt[cur][sd+3][scol]=vv[3];
    __syncthreads();                       // Vt[cur] visible; prev tile done with it

    // prefetch tile kt+1 (full tile of slack before consumption)
    bool pf = (kt + 1) < NT;
    short8 kn0 = {}, kn1 = {};
    ushort4v vn = {};
    if (pf){
      const unsigned short* ka = kaddr + (size_t)(kt+1)*1024;
      kn0 = *(const short8*)(ka);
      kn1 = *(const short8*)(ka + 512);
      vn  = *(const ushort4v*)(vsrc + (size_t)(kt+1)*1024);
    }

    // S^T = K Q^T : lane holds S[kv][q=lq], kv = 64kt + 32c + (r&3)+8(r>>2)+4hi
    f32x16 sA = __builtin_amdgcn_mfma_f32_32x32x16_bf16(kf0, qf, zero, 0, 0, 0);
    f32x16 sB = __builtin_amdgcn_mfma_f32_32x32x16_bf16(kf1, qf, zero, 0, 0, 0);

    // max-free softmax: P = exp2(S) directly
    #pragma unroll
    for (int r = 0; r < 16; ++r) sA[r] = __builtin_amdgcn_exp2f(sA[r]);
    #pragma unroll
    for (int r = 0; r < 16; ++r) sB[r] = __builtin_amdgcn_exp2f(sB[r]);

    // PV: 4 K=16 steps; A-frag = lane's own 8 P-regs; B-read unconditional
    auto pvstep = [&](const f32x16& pc, int h8, int vcol){
      uint4v pw;
      pw[0] = pack2bf(pc[h8+0], pc[h8+1]);
      pw[1] = pack2bf(pc[h8+2], pc[h8+3]);
      pw[2] = pack2bf(pc[h8+4], pc[h8+5]);
      pw[3] = pack2bf(pc[h8+6], pc[h8+7]);
      short8 pa = __builtin_bit_cast(short8, pw);
      short8 vf = *(const short8*)(&Vt[cur][lq][vcol + hi*8]);
      O = __builtin_amdgcn_mfma_f32_32x32x16_bf16(pa, vf, O, 0, 0, 0);
    };
    pvstep(sA, 0, 0);
    pvstep(sA, 8, 16);
    pvstep(sB, 0, 32);
    pvstep(sB, 8, 48);

    kf0 = kn0; kf1 = kn1; vv = vn;
  }

  // D[row=q][col]: col=lq (d for lq<16, lsum at col 16); row=(r&3)+8(r>>2)+4hi
  float* Op = part + (((size_t)sp*8 + bn)*4096 + qrow)*16;
  size_t lbase = ((size_t)sp*8 + bn)*4096 + qrow;
  #pragma unroll
  for (int r = 0; r < 16; ++r){
    int qr = (r&3) + 8*(r>>2) + 4*hi;
    if (lq < 16) __builtin_nontemporal_store(O[r], &Op[(size_t)qr*16 + lq]);
  }
  if (lq == 16){
    #pragma unroll
    for (int r = 0; r < 16; ++r){
      int qr = (r&3) + 8*(r>>2) + 4*hi;
      __builtin_nontemporal_store(O[r], &lsums[lbase + qr]);
    }
  }
}

// ---------------- K4: split-combine (plain sums) + out 1x1 conv + bias + residual ----------------
// grid 512 = b(2) x s-tile(256 of 16)
__global__ __launch_bounds__(256) void oproj_k(const float* __restrict__ part,
    const float* __restrict__ lsums, const float* __restrict__ wo,
    const float* __restrict__ bo, const float* __restrict__ x,
    float* __restrict__ out, int nsplit){
  int b  = blockIdx.x >> 8;
  int s0 = (blockIdx.x & 255) * 16;
  __shared__ float W[64][68];
  __shared__ float A[16][68];     // [s_local][c]
  int t = threadIdx.x;
  for (int i = t; i < 1024; i += 256){
    int o = i >> 4, c4 = (i & 15) * 4;
    *(float4*)&W[o][c4] = ((const float4*)wo)[i];
  }
  {
    int sl = t & 15;
    int u  = t >> 4;
    int n = u >> 2, d4 = (u & 3) * 4;
    size_t row = ((size_t)b*4 + n)*4096 + s0 + sl;
    float L = 0.f;
    for (int sp = 0; sp < nsplit; ++sp)
      L += __builtin_nontemporal_load(&lsums[(size_t)sp*32768 + row]);
    f32x4 acc = {0.f,0.f,0.f,0.f};
    for (int sp = 0; sp < nsplit; ++sp){
      f32x4 u0 = __builtin_nontemporal_load(
          (const f32x4*)(part + ((size_t)sp*32768 + row)*16 + d4));
      acc += u0;
    }
    float inv = 1.f / L;
    A[sl][n*16+d4+0] = acc[0]*inv; A[sl][n*16+d4+1] = acc[1]*inv;
    A[sl][n*16+d4+2] = acc[2]*inv; A[sl][n*16+d4+3] = acc[3]*inv;
  }
  __syncthreads();
  int sl = t & 15, grp = t >> 4;
  float acc[4] = {0.f,0.f,0.f,0.f};
  for (int c4 = 0; c4 < 16; ++c4){
    float4 a = *(const float4*)&A[sl][c4*4];
    #pragma unroll
    for (int j = 0; j < 4; ++j){
      float4 wv = *(const float4*)&W[grp + j*16][c4*4];
      acc[j] = fmaf(a.x, wv.x, fmaf(a.y, wv.y, fmaf(a.z, wv.z, fmaf(a.w, wv.w, acc[j]))));
    }
  }
  int s = s0 + sl;
  #pragma unroll
  for (int j = 0; j < 4; ++j){
    int o = grp + j*16;
    size_t idx = ((size_t)b*64 + o)*4096 + s;
    out[idx] = acc[j] + bo[o] + x[idx];
  }
}

extern "C" void kernel_launch(void* const* d_in, const int* in_sizes, int n_in,
                              void* d_out, int out_size, void* d_ws, size_t ws_size,
                              hipStream_t stream){
  const float* x   = (const float*)d_in[0];
  const float* gsc = (const float*)d_in[1];
  const float* gbi = (const float*)d_in[2];
  const float* wq  = (const float*)d_in[3];
  const float* wo  = (const float*)d_in[4];
  const float* bo  = (const float*)d_in[5];
  float* out = (float*)d_out;

  char* ws = (char*)d_ws;
  float* gp         = (float*)ws;                                   // 4 KB
  unsigned short* q = (unsigned short*)(ws + 8192);                 // 1 MB
  unsigned short* k = (unsigned short*)(ws + 8192 + 1048576);       // 1 MB
  unsigned short* v = (unsigned short*)(ws + 8192 + 2097152);       // 1 MB
  float* part       = (float*)(ws + 8192 + 3145728);                // nsplit*2 MB

  size_t need8 = 8192 + 3145728 + 8u*2097152 + 8u*131072;
  bool big = ws_size >= need8;
  int nsplit = big ? 8 : 4;
  float* lsums = (float*)(ws + 8192 + 3145728 + (size_t)nsplit*2097152);

  gn_partial_k<<<512,  256, 0, stream>>>(x, gp);
  qkv_k       <<<256,  256, 0, stream>>>(x, gp, gsc, gbi, wq, q, k, v);
  if (big) attn_k<3><<<2048, 256, 0, stream>>>(q, k, v, part, lsums);
  else     attn_k<2><<<1024, 256, 0, stream>>>(q, k, v, part, lsums);
  oproj_k     <<<512,  256, 0, stream>>>(part, lsums, wo, bo, x, out, nsplit);
}

// Round 6
// 55.676 us; speedup vs baseline: 3.1751x; 1.0901x over previous
//
#include <hip/hip_runtime.h>
#include <hip/hip_bf16.h>

typedef __attribute__((ext_vector_type(8))) short short8;
typedef __attribute__((ext_vector_type(4))) float f32x4;
typedef __attribute__((ext_vector_type(16))) float f32x16;
typedef __attribute__((ext_vector_type(4))) unsigned int uint4v;

#define DEV static __device__ __forceinline__

DEV unsigned short f2bf(float f){
  unsigned u = __float_as_uint(f);
  u += 0x7fffu + ((u >> 16) & 1u);
  return (unsigned short)(u >> 16);
}

DEV unsigned pack2bf(float a, float b){
  __hip_bfloat162 h = __float22bfloat162_rn(make_float2(a, b));
  unsigned u;
  __builtin_memcpy(&u, &h, 4);
  return u;
}

// B=2, C=64, H=W=64 -> S=4096, NH=4, HD=16, GROUPS=32
#define QSCALE 0.180336880111f   // 0.125 * log2(e); softmax in exp2 domain, max-free
#define NSPLIT 4
#define NT 16                    // KV tiles (of 64) per split

// ---------------- K1: GroupNorm partial sums (512 blocks = 64 groups x 8) ----------------
__global__ __launch_bounds__(256) void gn_partial_k(const float* __restrict__ x,
                                                    float* __restrict__ gp){
  int blk = blockIdx.x;
  float4 v = ((const float4*)(x + (size_t)blk*1024))[threadIdx.x];
  float s = v.x+v.y+v.z+v.w;
  float q = v.x*v.x+v.y*v.y+v.z*v.z+v.w*v.w;
  #pragma unroll
  for (int off = 1; off < 64; off <<= 1){
    s += __shfl_xor(s, off);
    q += __shfl_xor(q, off);
  }
  __shared__ float red[8];
  int w = threadIdx.x >> 6;
  if ((threadIdx.x & 63) == 0){ red[w*2] = s; red[w*2+1] = q; }
  __syncthreads();
  if (threadIdx.x == 0){
    gp[blk*2+0] = red[0]+red[2]+red[4]+red[6];
    gp[blk*2+1] = red[1]+red[3]+red[5]+red[7];
  }
}

// ---------------- K2: GN finalize + GN-apply + QKV 1x1 conv -> bf16 ----------------
// q,k: [bn][s][d=16] (q pre-scaled by QSCALE).
// vt : [bn][row=32][s=4096] transposed V with sigma (kv bit2<->bit3 swap) applied
//      to the s index; row 16 = constant bf16 1.0 (lsum column for attn PV MFMA).
__global__ __launch_bounds__(256) void qkv_k(const float* __restrict__ x,
    const float* __restrict__ gp, const float* __restrict__ gsc,
    const float* __restrict__ gbi, const float* __restrict__ wq,
    unsigned short* __restrict__ q, unsigned short* __restrict__ k,
    unsigned short* __restrict__ vt){
  int b  = blockIdx.x >> 7;
  int s0 = (blockIdx.x & 127) * 32;
  __shared__ float W[192][68];    // padded: bank-conflict-free o-reads
  __shared__ float A[32][68];     // [s_local][c]
  __shared__ float MS[32][2];     // per-group mean, rstd
  int t = threadIdx.x;
  for (int i = t; i < 3072; i += 256){
    int o = i >> 4, c4 = (i & 15) * 4;
    *(float4*)&W[o][c4] = ((const float4*)wq)[i];
  }
  if (t < 32){
    float s = 0.f, ss = 0.f;
    #pragma unroll
    for (int i = 0; i < 8; ++i){
      const float* pp = gp + ((b*32 + t)*8 + i)*2;
      s += pp[0]; ss += pp[1];
    }
    float mean = s * (1.f/8192.f);
    MS[t][0] = mean;
    MS[t][1] = rsqrtf(ss * (1.f/8192.f) - mean*mean + 1e-5f);
  }
  // ones row for vt (row 16 of each bn)
  if (t < 128){
    int n = t >> 5, si = t & 31;
    vt[((size_t)(b*4 + n)*32 + 16)*4096 + s0 + si] = (unsigned short)0x3F80;
  }
  __syncthreads();
  {
    int c  = t >> 2;
    int s8 = (t & 3) * 8;
    const float* px = x + ((size_t)b*64 + c)*4096 + s0 + s8;
    float4 v0 = *(const float4*)px;
    float4 v1 = *(const float4*)(px + 4);
    float sc = gsc[c] * MS[c>>1][1];
    float bi = gbi[c] - MS[c>>1][0] * sc;
    A[s8+0][c]=v0.x*sc+bi; A[s8+1][c]=v0.y*sc+bi; A[s8+2][c]=v0.z*sc+bi; A[s8+3][c]=v0.w*sc+bi;
    A[s8+4][c]=v1.x*sc+bi; A[s8+5][c]=v1.y*sc+bi; A[s8+6][c]=v1.z*sc+bi; A[s8+7][c]=v1.w*sc+bi;
  }
  __syncthreads();
  int sl = t >> 3, grp = t & 7;
  float acc[24];
  #pragma unroll
  for (int j = 0; j < 24; ++j) acc[j] = 0.f;
  for (int c4 = 0; c4 < 16; ++c4){
    float4 a = *(const float4*)&A[sl][c4*4];
    #pragma unroll
    for (int j = 0; j < 24; ++j){
      float4 wv = *(const float4*)&W[grp + j*8][c4*4];
      acc[j] = fmaf(a.x, wv.x, fmaf(a.y, wv.y, fmaf(a.z, wv.z, fmaf(a.w, wv.w, acc[j]))));
    }
  }
  int s = s0 + sl;
  // sigma(sl): swap bits 2 and 3 (involution; matches attn PV A-frag reg order)
  int slp = (sl & 0x13) | (((sl >> 2) & 1) << 3) | (((sl >> 3) & 1) << 2);
  #pragma unroll
  for (int j = 0; j < 24; ++j){
    int o = grp + j*8;
    int n = o / 48, r = o % 48;
    float val = acc[j];
    if (r < 16){
      q[((((size_t)b*4 + n)*4096 + s))*16 + r] = f2bf(val * QSCALE);
    } else if (r < 32){
      k[((((size_t)b*4 + n)*4096 + s))*16 + r - 16] = f2bf(val);
    } else {
      vt[((size_t)(b*4 + n)*32 + (r - 32))*4096 + s0 + slp] = f2bf(val);
    }
  }
}

// ---------------- K3: flash attention — barrier-free, LDS-free ----------------
// grid 1024 = qt(32) x sp(4) x bn(8), bn = blk&7 (XCD-local K/V working set).
// 4 independent waves/block; wave w owns q rows qt*128+w*32..+31.
// S^T = mfma(K,Q) -> lane holds S[kv][q=lq]; P = exp2(S) (max-free).
// PV B-frags load straight from vt (pre-transposed+permuted); row 16 = ones
// accumulates lsum in O column 16. Lanes 17-31 clamp to the ones row.
__global__ __launch_bounds__(256) void attn_k(const unsigned short* __restrict__ qb,
    const unsigned short* __restrict__ kb, const unsigned short* __restrict__ vt,
    float* __restrict__ part, float* __restrict__ lsums){
  int blk = blockIdx.x;
  int bn = blk & 7;
  int sp = (blk >> 3) & (NSPLIT - 1);
  int qt = blk >> 5;
  int t = threadIdx.x, w = t >> 6, l = t & 63;
  int lq = l & 31, hi = l >> 5;

  const unsigned short* Kp = kb + ((size_t)bn*4096 + sp*(NT*64))*16;
  int vrow = (lq < 16) ? lq : 16;
  const unsigned short* Vr = vt + ((size_t)bn*32 + vrow)*4096 + sp*(NT*64) + hi*8;
  int qrow = qt*128 + w*32;
  const unsigned short* Qp = qb + ((size_t)bn*4096 + qrow)*16;

  // Q as B-frag: lane holds Q[q=lq][d=8hi+j]
  short8 qf = *(const short8*)(Qp + (size_t)lq*16 + hi*8);
  const unsigned short* kaddr = Kp + (size_t)lq*16 + hi*8;

  f32x16 O, zero;
  #pragma unroll
  for (int r = 0; r < 16; ++r){ O[r] = 0.f; zero[r] = 0.f; }

  // prologue: tile 0 fragments
  short8 kf0 = *(const short8*)(kaddr);
  short8 kf1 = *(const short8*)(kaddr + 512);
  short8 vf0 = *(const short8*)(Vr);
  short8 vf1 = *(const short8*)(Vr + 16);
  short8 vf2 = *(const short8*)(Vr + 32);
  short8 vf3 = *(const short8*)(Vr + 48);

  for (int kt = 0; kt < NT; ++kt){
    // prefetch tile kt+1 (consumed next iter; ~full tile of slack)
    bool pf = (kt + 1) < NT;
    short8 kn0 = {}, kn1 = {}, vn0 = {}, vn1 = {}, vn2 = {}, vn3 = {};
    if (pf){
      const unsigned short* ka = kaddr + (size_t)(kt+1)*1024;
      kn0 = *(const short8*)(ka);
      kn1 = *(const short8*)(ka + 512);
      const unsigned short* va = Vr + (size_t)(kt+1)*64;
      vn0 = *(const short8*)(va);
      vn1 = *(const short8*)(va + 16);
      vn2 = *(const short8*)(va + 32);
      vn3 = *(const short8*)(va + 48);
    }

    // S^T = K Q^T : lane holds S[kv][q=lq], kv = 64kt + 32c + (r&3)+8(r>>2)+4hi
    f32x16 sA = __builtin_amdgcn_mfma_f32_32x32x16_bf16(kf0, qf, zero, 0, 0, 0);
    f32x16 sB = __builtin_amdgcn_mfma_f32_32x32x16_bf16(kf1, qf, zero, 0, 0, 0);

    // max-free softmax: P = exp2(S) directly
    #pragma unroll
    for (int r = 0; r < 16; ++r) sA[r] = __builtin_amdgcn_exp2f(sA[r]);
    #pragma unroll
    for (int r = 0; r < 16; ++r) sB[r] = __builtin_amdgcn_exp2f(sB[r]);

    // PV: 4 K=16 steps; A-frag = lane's own 8 P-regs (cvt_pk only)
    auto pvstep = [&](const f32x16& pc, int h8, short8 vf){
      uint4v pw;
      pw[0] = pack2bf(pc[h8+0], pc[h8+1]);
      pw[1] = pack2bf(pc[h8+2], pc[h8+3]);
      pw[2] = pack2bf(pc[h8+4], pc[h8+5]);
      pw[3] = pack2bf(pc[h8+6], pc[h8+7]);
      short8 pa = __builtin_bit_cast(short8, pw);
      O = __builtin_amdgcn_mfma_f32_32x32x16_bf16(pa, vf, O, 0, 0, 0);
    };
    pvstep(sA, 0, vf0);
    pvstep(sA, 8, vf1);
    pvstep(sB, 0, vf2);
    pvstep(sB, 8, vf3);

    kf0 = kn0; kf1 = kn1;
    vf0 = vn0; vf1 = vn1; vf2 = vn2; vf3 = vn3;
  }

  // D[row=q][col]: col=lq (d for lq<16, lsum at col 16); row=(r&3)+8(r>>2)+4hi
  float* Op = part + (((size_t)sp*8 + bn)*4096 + qrow)*16;
  size_t lbase = ((size_t)sp*8 + bn)*4096 + qrow;
  #pragma unroll
  for (int r = 0; r < 16; ++r){
    int qr = (r&3) + 8*(r>>2) + 4*hi;
    if (lq < 16) __builtin_nontemporal_store(O[r], &Op[(size_t)qr*16 + lq]);
  }
  if (lq == 16){
    #pragma unroll
    for (int r = 0; r < 16; ++r){
      int qr = (r&3) + 8*(r>>2) + 4*hi;
      __builtin_nontemporal_store(O[r], &lsums[lbase + qr]);
    }
  }
}

// ---------------- K4: split-combine (plain sums) + out 1x1 conv + bias + residual ----------------
// grid 512 = b(2) x s-tile(256 of 16)
__global__ __launch_bounds__(256) void oproj_k(const float* __restrict__ part,
    const float* __restrict__ lsums, const float* __restrict__ wo,
    const float* __restrict__ bo, const float* __restrict__ x,
    float* __restrict__ out){
  int b  = blockIdx.x >> 8;
  int s0 = (blockIdx.x & 255) * 16;
  __shared__ float W[64][68];
  __shared__ float A[16][68];     // [s_local][c]
  int t = threadIdx.x;
  for (int i = t; i < 1024; i += 256){
    int o = i >> 4, c4 = (i & 15) * 4;
    *(float4*)&W[o][c4] = ((const float4*)wo)[i];
  }
  {
    int sl = t & 15;
    int u  = t >> 4;
    int n = u >> 2, d4 = (u & 3) * 4;
    size_t row = ((size_t)b*4 + n)*4096 + s0 + sl;
    float L = 0.f;
    #pragma unroll
    for (int sp = 0; sp < NSPLIT; ++sp)
      L += __builtin_nontemporal_load(&lsums[(size_t)sp*32768 + row]);
    f32x4 acc = {0.f,0.f,0.f,0.f};
    #pragma unroll
    for (int sp = 0; sp < NSPLIT; ++sp){
      f32x4 u0 = __builtin_nontemporal_load(
          (const f32x4*)(part + ((size_t)sp*32768 + row)*16 + d4));
      acc += u0;
    }
    float inv = 1.f / L;
    A[sl][n*16+d4+0] = acc[0]*inv; A[sl][n*16+d4+1] = acc[1]*inv;
    A[sl][n*16+d4+2] = acc[2]*inv; A[sl][n*16+d4+3] = acc[3]*inv;
  }
  __syncthreads();
  int sl = t & 15, grp = t >> 4;
  float acc[4] = {0.f,0.f,0.f,0.f};
  for (int c4 = 0; c4 < 16; ++c4){
    float4 a = *(const float4*)&A[sl][c4*4];
    #pragma unroll
    for (int j = 0; j < 4; ++j){
      float4 wv = *(const float4*)&W[grp + j*16][c4*4];
      acc[j] = fmaf(a.x, wv.x, fmaf(a.y, wv.y, fmaf(a.z, wv.z, fmaf(a.w, wv.w, acc[j]))));
    }
  }
  int s = s0 + sl;
  #pragma unroll
  for (int j = 0; j < 4; ++j){
    int o = grp + j*16;
    size_t idx = ((size_t)b*64 + o)*4096 + s;
    out[idx] = acc[j] + bo[o] + x[idx];
  }
}

extern "C" void kernel_launch(void* const* d_in, const int* in_sizes, int n_in,
                              void* d_out, int out_size, void* d_ws, size_t ws_size,
                              hipStream_t stream){
  const float* x   = (const float*)d_in[0];
  const float* gsc = (const float*)d_in[1];
  const float* gbi = (const float*)d_in[2];
  const float* wq  = (const float*)d_in[3];
  const float* wo  = (const float*)d_in[4];
  const float* bo  = (const float*)d_in[5];
  float* out = (float*)d_out;

  char* ws = (char*)d_ws;
  float* gp          = (float*)ws;                                  // 4 KB
  unsigned short* q  = (unsigned short*)(ws + 8192);                // 1 MB
  unsigned short* k  = (unsigned short*)(ws + 8192 + 1048576);      // 1 MB
  unsigned short* vt = (unsigned short*)(ws + 8192 + 2097152);      // 2 MB (8bn x 32 x 4096)
  float* part        = (float*)(ws + 8192 + 4194304);               // 8 MB
  float* lsums       = (float*)(ws + 8192 + 4194304 + 8388608);     // 512 KB

  gn_partial_k<<<512,  256, 0, stream>>>(x, gp);
  qkv_k       <<<256,  256, 0, stream>>>(x, gp, gsc, gbi, wq, q, k, vt);
  attn_k      <<<1024, 256, 0, stream>>>(q, k, vt, part, lsums);
  oproj_k     <<<512,  256, 0, stream>>>(part, lsums, wo, bo, x, out);
}